// Round 11
// baseline (282.840 us; speedup 1.0000x reference)
//
#include <hip/hip_runtime.h>
#include <hip/hip_fp16.h>

#define NN 50000
#define NE 500000
#define D  128
#define OD 64
#define NG 512

typedef __attribute__((ext_vector_type(8))) short s8v;        // 8×16b (16B)
typedef __attribute__((ext_vector_type(4))) float f4v;        // MFMA acc
typedef _Float16 f16x8 __attribute__((ext_vector_type(8)));   // 8 fp16 (4 VGPR)

struct H4 { __half2 a, b; };                  // 4 fp16 = 8B
struct __align__(8) ER { int r; float w; };   // edge record

// ---------------- fused setup: zero counts, pack W1-3 (fp16 hi + 2^11*lo), comb W4@Wfc, x->fp16 ----------------
__global__ __launch_bounds__(256) void k_setup(const float* __restrict__ x,
                                               const float* __restrict__ w0,
                                               const float* __restrict__ w1,
                                               const float* __restrict__ w2,
                                               const float* __restrict__ W4,
                                               const float* __restrict__ Wfc,
                                               const float* __restrict__ b4,
                                               const float* __restrict__ bfc,
                                               int* __restrict__ counts,
                                               unsigned short* __restrict__ wpk,
                                               float* __restrict__ Wcomb,
                                               float* __restrict__ bcomb,
                                               __half* __restrict__ xh) {
    int b = blockIdx.x, t = threadIdx.x;
    if (b < 24) {                          // zero counts (50176 ints)
        for (int i = b * 256 + t; i < NN + 176; i += 24 * 256) counts[i] = 0;
    } else if (b < 48) {                   // pack W1-3 into B-frag fp16 hi/lo layout
        int idx = b - 24;
        int layer = idx >> 3, chunk = idx & 7;
        const float* W = (layer == 0) ? w0 : (layer == 1) ? w1 : w2;
        unsigned short* hi = wpk + layer * 32768;
        unsigned short* lo = hi + 16384;
        for (int it = 0; it < 8; ++it) {
            int p = chunk * 2048 + it * 256 + t;
            int j = p & 7, lane = (p >> 3) & 63, s = (p >> 9) & 3, nt = p >> 11;
            int k = s * 32 + ((lane >> 4) << 3) + j;
            int n = nt * 16 + (lane & 15);
            float v = W[k * D + n];
            __half h = __float2half_rn(v);
            hi[p] = __half_as_ushort(h);
            float resid = (v - __half2float(h)) * 2048.0f;   // scale keeps lo normal-range
            lo[p] = __half_as_ushort(__float2half_rn(resid));
        }
    } else if (b < 56) {                   // Wcomb = W4@Wfc ; bcomb = b4@Wfc + bfc
        int id = (b - 48) * 256 + t;       // 2048 threads
        #pragma unroll
        for (int q = 0; q < 4; ++q) {
            int p = id + q * 2048;         // 8192 outputs
            int k = p >> 6, n = p & 63;
            float s = 0.f;
            for (int j = 0; j < D; ++j) s += W4[k * D + j] * Wfc[j * OD + n];
            Wcomb[p] = s;
        }
        if (id < OD) {
            float s = bfc[id];
            for (int j = 0; j < D; ++j) s += b4[j] * Wfc[j * OD + id];
            bcomb[id] = s;
        }
    } else {                               // x -> fp16
        for (int i = (b - 56) * 256 + t; i < NN * D / 4; i += 1600 * 256) {
            float4 v = ((const float4*)x)[i];
            H4 o;
            o.a = __floats2half2_rn(v.x, v.y);
            o.b = __floats2half2_rn(v.z, v.w);
            ((H4*)xh)[i] = o;
        }
    }
}

// ---------------- CSR build ----------------
__global__ void k_count_rank(const int* __restrict__ col,
                             int* __restrict__ counts, int* __restrict__ rank) {
    int e = blockIdx.x * blockDim.x + threadIdx.x;
    if (e < NE) rank[e] = atomicAdd(&counts[col[e]], 1);
}

__global__ __launch_bounds__(256) void k_scan_blk(const int* __restrict__ counts,
                                                  int* __restrict__ offs,
                                                  int* __restrict__ bsum) {
    __shared__ int tmp[256];
    int b = blockIdx.x, t = threadIdx.x;
    int i = b * 256 + t;
    int v = (i < NN) ? counts[i] : 0;
    tmp[t] = v;
    __syncthreads();
    for (int st = 1; st < 256; st <<= 1) {
        int u = (t >= st) ? tmp[t - st] : 0;
        __syncthreads();
        tmp[t] += u;
        __syncthreads();
    }
    if (i < NN) offs[i] = tmp[t] - v;
    if (t == 255) bsum[b] = tmp[255];
}

__global__ __launch_bounds__(256) void k_scan_top(const int* __restrict__ bsum,
                                                  int* __restrict__ bbase, int nb) {
    __shared__ int tmp[256];
    int t = threadIdx.x;
    int v = (t < nb) ? bsum[t] : 0;
    tmp[t] = v;
    __syncthreads();
    for (int st = 1; st < 256; st <<= 1) {
        int u = (t >= st) ? tmp[t - st] : 0;
        __syncthreads();
        tmp[t] += u;
        __syncthreads();
    }
    if (t < nb) bbase[t] = tmp[t] - v;
}

__global__ __launch_bounds__(256) void k_scan_add(int* __restrict__ offs,
                                                  const int* __restrict__ bbase) {
    int b = blockIdx.x, t = threadIdx.x;
    int i = b * 256 + t;
    if (i < NN) offs[i] += bbase[b];
    if (b == 0 && t == 0) offs[NN] = NE;
}

__global__ void k_fill2(const int* __restrict__ row, const int* __restrict__ col,
                        const float* __restrict__ ew, const int* __restrict__ offs,
                        const int* __restrict__ rank, ER* __restrict__ esr) {
    int e = blockIdx.x * blockDim.x + threadIdx.x;
    if (e < NE) {
        ER v;
        v.r = row[e];
        v.w = ew[e];
        esr[offs[col[e]] + rank[e]] = v;
    }
}

__global__ void k_deg_csr(const ER* __restrict__ esr, const int* __restrict__ offs,
                          float* __restrict__ dinv, float* __restrict__ selfc) {
    int i = blockIdx.x * blockDim.x + threadIdx.x;
    if (i < NN) {
        float s = 1.0f;
        int a = offs[i], b = offs[i + 1];
        for (int j = a; j < b; ++j) s += esr[j].w;
        float r = rsqrtf(s);
        dinv[i] = r;
        selfc[i] = r * r;
    }
}

// ---------------- fused agg + GEMM: Hout = relu((A_hat @ Hin) @ W + b) ----------------
// Phase 1: 8 half-waves aggregate 64 nodes (8 rounds) into padded LDS (272B row stride).
// Phase 2: 4 waves x one 16-row MFMA tile each; fp16 2-term W from L2.
// NORM=1 (layer 1): normalize esr.w in place (w = dinv[c]*ew*dinv[r]).
template <int NORM>
__global__ __launch_bounds__(256) void k_agg_gemm(const __half* __restrict__ Hin,
                                                  const int* __restrict__ offs,
                                                  ER* __restrict__ esr,
                                                  const float* __restrict__ dinv,
                                                  const float* __restrict__ selfc,
                                                  const unsigned short* __restrict__ Wh,
                                                  const unsigned short* __restrict__ Wl,
                                                  const float* __restrict__ bias,
                                                  __half* __restrict__ Hout) {
    __shared__ __half Asl[64 * 136];           // 64 rows x 272B (pad kills bank conflicts)
    int tid = threadIdx.x;
    int hw = tid >> 5, ln = tid & 31;
    int l4 = ln * 4;
    int rbase = blockIdx.x * 64;

    // ---- phase 1: aggregate ----
    for (int rnd = 0; rnd < 8; ++rnd) {
        int lrow = rnd * 8 + hw;
        int node = rbase + lrow;
        float ax = 0.f, ay = 0.f, az = 0.f, aw = 0.f;
        if (node < NN) {
            H4 sv = *(const H4*)(Hin + (size_t)node * D + l4);
            float2 s0 = __half22float2(sv.a), s1 = __half22float2(sv.b);
            float sc = selfc[node];
            ax = sc * s0.x; ay = sc * s0.y; az = sc * s1.x; aw = sc * s1.y;
            int s = offs[node], e = offs[node + 1];
            float di = NORM ? dinv[node] : 0.f;
            int j = s;
            for (; j + 8 <= e; j += 8) {
                ER er[8];
                #pragma unroll
                for (int q = 0; q < 8; ++q) er[q] = esr[j + q];
                if (NORM) {
                    #pragma unroll
                    for (int q = 0; q < 8; ++q) er[q].w = di * er[q].w * dinv[er[q].r];
                }
                H4 v[8];
                #pragma unroll
                for (int q = 0; q < 8; ++q) v[q] = *(const H4*)(Hin + (size_t)er[q].r * D + l4);
                if (NORM && ln == 0) {
                    #pragma unroll
                    for (int q = 0; q < 8; ++q) esr[j + q].w = er[q].w;
                }
                #pragma unroll
                for (int q = 0; q < 8; ++q) {
                    float w = er[q].w;
                    float2 p0 = __half22float2(v[q].a), p1 = __half22float2(v[q].b);
                    ax += w * p0.x; ay += w * p0.y; az += w * p1.x; aw += w * p1.y;
                }
            }
            for (; j < e; ++j) {
                ER er = esr[j];
                if (NORM) {
                    er.w = di * er.w * dinv[er.r];
                    if (ln == 0) esr[j].w = er.w;
                }
                H4 v0 = *(const H4*)(Hin + (size_t)er.r * D + l4);
                float2 p0 = __half22float2(v0.a), p1 = __half22float2(v0.b);
                ax += er.w * p0.x; ay += er.w * p0.y; az += er.w * p1.x; aw += er.w * p1.y;
            }
        }
        H4 o;
        o.a = __floats2half2_rn(ax, ay);
        o.b = __floats2half2_rn(az, aw);
        *(H4*)(&Asl[lrow * 136 + l4]) = o;
    }
    __syncthreads();

    // ---- phase 2: MFMA ----
    int w = tid >> 6;
    int lane = tid & 63;
    int trow = w * 16;
    int kg = (lane >> 4) << 3;
    f16x8 Af[4];
    #pragma unroll
    for (int s = 0; s < 4; ++s)
        Af[s] = *(const f16x8*)(&Asl[(trow + (lane & 15)) * 136 + s * 32 + kg]);

    const _Float16* whp = (const _Float16*)Wh;
    const _Float16* wlp = (const _Float16*)Wl;
    int cb = lane & 15;
    int rb = rbase + trow + ((lane >> 4) << 2);
    #pragma unroll
    for (int nt = 0; nt < 8; ++nt) {
        f4v acc1 = {0.f, 0.f, 0.f, 0.f};
        f4v acc2 = {0.f, 0.f, 0.f, 0.f};
        #pragma unroll
        for (int s = 0; s < 4; ++s) {
            int off = ((nt * 4 + s) * 64 + lane) * 8;
            f16x8 bh = *(const f16x8*)(whp + off);
            f16x8 bl = *(const f16x8*)(wlp + off);
            acc1 = __builtin_amdgcn_mfma_f32_16x16x32_f16(Af[s], bh, acc1, 0, 0, 0);
            acc2 = __builtin_amdgcn_mfma_f32_16x16x32_f16(Af[s], bl, acc2, 0, 0, 0);
        }
        float bv = bias[nt * 16 + cb];
        #pragma unroll
        for (int q = 0; q < 4; ++q) {
            int rr = rb + q;
            if (rr < NN) {
                float v = fmaxf(acc1[q] + acc2[q] * (1.0f / 2048.0f) + bv, 0.f);
                Hout[(size_t)rr * D + nt * 16 + cb] = __float2half(v);
            }
        }
    }
}

// ---------------- final aggregation (layer 4, no GEMM): fp16 in/out ----------------
__global__ __launch_bounds__(256) void k_agg(const __half* __restrict__ Hm,
                                             const int* __restrict__ offs,
                                             const ER* __restrict__ esr,
                                             const float* __restrict__ selfc,
                                             __half* __restrict__ out) {
    int node = blockIdx.x * 8 + (threadIdx.x >> 5);
    if (node >= NN) return;
    int l4 = (threadIdx.x & 31) * 4;
    H4 sv = *(const H4*)(Hm + (size_t)node * D + l4);
    float2 s0 = __half22float2(sv.a), s1 = __half22float2(sv.b);
    float sc = selfc[node];
    float ax = sc * s0.x, ay = sc * s0.y, az = sc * s1.x, aw = sc * s1.y;
    int s = offs[node], e = offs[node + 1];
    int j = s;
    for (; j + 8 <= e; j += 8) {
        ER er[8];
        #pragma unroll
        for (int q = 0; q < 8; ++q) er[q] = esr[j + q];
        H4 v[8];
        #pragma unroll
        for (int q = 0; q < 8; ++q) v[q] = *(const H4*)(Hm + (size_t)er[q].r * D + l4);
        #pragma unroll
        for (int q = 0; q < 8; ++q) {
            float w = er[q].w;
            float2 p0 = __half22float2(v[q].a), p1 = __half22float2(v[q].b);
            ax += w * p0.x; ay += w * p0.y; az += w * p1.x; aw += w * p1.y;
        }
    }
    for (; j < e; ++j) {
        ER er = esr[j];
        H4 v0 = *(const H4*)(Hm + (size_t)er.r * D + l4);
        float2 p0 = __half22float2(v0.a), p1 = __half22float2(v0.b);
        ax += er.w * p0.x; ay += er.w * p0.y; az += er.w * p1.x; aw += er.w * p1.y;
    }
    H4 o;
    o.a = __floats2half2_rn(ax, ay);
    o.b = __floats2half2_rn(az, aw);
    *(H4*)(out + (size_t)node * D + l4) = o;
}

// ---------------- fused mean-pool + output GEMM ----------------
__global__ __launch_bounds__(128) void k_poolout(const __half* __restrict__ Hm,
                                                 const int* __restrict__ batch,
                                                 const float* __restrict__ Wcomb,
                                                 const float* __restrict__ bcomb,
                                                 float* __restrict__ outp) {
    __shared__ float prow[D];
    __shared__ int seb[2];
    int g = blockIdx.x, t = threadIdx.x;
    if (t < 2) {
        int target = g + t;
        int lo = 0, hi = NN;
        while (lo < hi) {
            int mid = (lo + hi) >> 1;
            if (batch[mid] < target) lo = mid + 1; else hi = mid;
        }
        seb[t] = lo;
    }
    __syncthreads();
    int s = seb[0], e = seb[1];
    float a0 = 0.f, a1 = 0.f, a2 = 0.f, a3 = 0.f;
    int n = s;
    for (; n + 4 <= e; n += 4) {
        a0 += __half2float(Hm[(size_t)(n + 0) * D + t]);
        a1 += __half2float(Hm[(size_t)(n + 1) * D + t]);
        a2 += __half2float(Hm[(size_t)(n + 2) * D + t]);
        a3 += __half2float(Hm[(size_t)(n + 3) * D + t]);
    }
    for (; n < e; ++n) a0 += __half2float(Hm[(size_t)n * D + t]);
    float inv = 1.0f / (float)max(e - s, 1);
    prow[t] = (a0 + a1 + a2 + a3) * inv;
    __syncthreads();
    if (t < OD) {
        float acc = bcomb[t];
        #pragma unroll 4
        for (int k = 0; k < D; ++k) acc += prow[k] * Wcomb[k * OD + t];
        outp[g * OD + t] = acc;
    }
}

// ---------------- launch ----------------

extern "C" void kernel_launch(void* const* d_in, const int* in_sizes, int n_in,
                              void* d_out, int out_size, void* d_ws, size_t ws_size,
                              hipStream_t stream) {
    const float* x    = (const float*)d_in[0];
    const int*   ei   = (const int*)d_in[1];
    const int*   row  = ei;
    const int*   col  = ei + NE;
    const float* ew   = (const float*)d_in[2];
    const int*   batch= (const int*)d_in[3];
    const float* W1 = (const float*)d_in[4];  const float* b1 = (const float*)d_in[5];
    const float* W2 = (const float*)d_in[6];  const float* b2 = (const float*)d_in[7];
    const float* W3 = (const float*)d_in[8];  const float* b3 = (const float*)d_in[9];
    const float* W4 = (const float*)d_in[10]; const float* b4 = (const float*)d_in[11];
    const float* Wfc= (const float*)d_in[12]; const float* bfc= (const float*)d_in[13];

    float* ws = (float*)d_ws;
    float* dinv   = ws + 0;                  // 50048
    float* selfc  = ws + 50048;              // 50048
    int*   counts = (int*)(ws + 100096);     // 50176
    int*   offs   = (int*)(ws + 150272);     // 50176
    int*   rank   = (int*)(ws + 200448);     // 500000
    ER*    esr    = (ER*)(ws + 700448);      // 500000 * 8B
    __half* xh    = (__half*)(ws + 1700448); // 6.4M fp16
    __half* bufA  = (__half*)(ws + 4900448); // 6.4M fp16
    __half* bufB  = (__half*)(ws + 8100448); // 6.4M fp16
    unsigned short* wpk = (unsigned short*)(ws + 11300448);  // 3*32768 ushort
    float* wcomb  = ws + 11349600;           // 8192
    float* bcomb  = ws + 11357792;           // 64
    int*   bsum   = (int*)(ws + 11357856);   // 256
    int*   bbase  = (int*)(ws + 11358112);   // 256

    const int TB = 256;
    int nblk = (NN + TB - 1) / TB;   // 196
    int eblk = (NE + TB - 1) / TB;   // 1954

    // fused setup, then CSR build
    k_setup<<<1656, 256, 0, stream>>>(x, W1, W2, W3, W4, Wfc, b4, bfc,
                                      counts, wpk, wcomb, bcomb, xh);
    k_count_rank<<<eblk, TB, 0, stream>>>(col, counts, rank);
    k_scan_blk<<<nblk, 256, 0, stream>>>(counts, offs, bsum);
    k_scan_top<<<1, 256, 0, stream>>>(bsum, bbase, nblk);
    k_scan_add<<<nblk, 256, 0, stream>>>(offs, bbase);
    k_fill2<<<eblk, TB, 0, stream>>>(row, col, ew, offs, rank, esr);
    k_deg_csr<<<nblk, TB, 0, stream>>>(esr, offs, dinv, selfc);

    const int FB = (NN + 63) / 64;       // 782 fused blocks
    const int AB = (NN + 7) / 8;         // 6250 agg blocks

    unsigned short* w1h = wpk;           unsigned short* w1l = wpk + 16384;
    unsigned short* w2h = wpk + 32768;   unsigned short* w2l = wpk + 49152;
    unsigned short* w3h = wpk + 65536;   unsigned short* w3l = wpk + 81920;

    // layers 1-3 fused (layer 1 also normalizes esr.w in place)
    k_agg_gemm<1><<<FB, 256, 0, stream>>>(xh,   offs, esr, dinv, selfc, w1h, w1l, b1, bufA);
    k_agg_gemm<0><<<FB, 256, 0, stream>>>(bufA, offs, esr, dinv, selfc, w2h, w2l, b2, bufB);
    k_agg_gemm<0><<<FB, 256, 0, stream>>>(bufB, offs, esr, dinv, selfc, w3h, w3l, b3, xh);

    // layer 4 aggregation + fused pool/out (W4,Wfc folded into Wcomb)
    k_agg<<<AB, 256, 0, stream>>>(xh, offs, esr, selfc, bufA);
    k_poolout<<<NG, 128, 0, stream>>>(bufA, batch, wcomb, bcomb, (float*)d_out);
}

// Round 12
// 236.342 us; speedup vs baseline: 1.1967x; 1.1967x over previous
//
#include <hip/hip_runtime.h>
#include <hip/hip_fp16.h>

#define NN 50000
#define NE 500000
#define D  128
#define OD 64
#define NG 512

typedef __attribute__((ext_vector_type(4))) float f4v;        // MFMA acc
typedef _Float16 f16x8 __attribute__((ext_vector_type(8)));   // 8 fp16 (4 VGPR)

struct H4 { __half2 a, b; };                  // 4 fp16 = 8B
struct __align__(8) ER { int r; float w; };   // edge record

// ---------------- fused setup: zero counts, pack W1-3 (fp16 hi + 2^11*lo), comb W4@Wfc, x->fp16 ----------------
__global__ __launch_bounds__(256) void k_setup(const float* __restrict__ x,
                                               const float* __restrict__ w0,
                                               const float* __restrict__ w1,
                                               const float* __restrict__ w2,
                                               const float* __restrict__ W4,
                                               const float* __restrict__ Wfc,
                                               const float* __restrict__ b4,
                                               const float* __restrict__ bfc,
                                               int* __restrict__ counts,
                                               unsigned short* __restrict__ wpk,
                                               float* __restrict__ Wcomb,
                                               float* __restrict__ bcomb,
                                               __half* __restrict__ xh) {
    int b = blockIdx.x, t = threadIdx.x;
    if (b < 24) {                          // zero counts (50176 ints)
        for (int i = b * 256 + t; i < NN + 176; i += 24 * 256) counts[i] = 0;
    } else if (b < 48) {                   // pack W1-3 into B-frag fp16 hi/lo layout
        int idx = b - 24;
        int layer = idx >> 3, chunk = idx & 7;
        const float* W = (layer == 0) ? w0 : (layer == 1) ? w1 : w2;
        unsigned short* hi = wpk + layer * 32768;
        unsigned short* lo = hi + 16384;
        for (int it = 0; it < 8; ++it) {
            int p = chunk * 2048 + it * 256 + t;
            int j = p & 7, lane = (p >> 3) & 63, s = (p >> 9) & 3, nt = p >> 11;
            int k = s * 32 + ((lane >> 4) << 3) + j;
            int n = nt * 16 + (lane & 15);
            float v = W[k * D + n];
            __half h = __float2half_rn(v);
            hi[p] = __half_as_ushort(h);
            float resid = (v - __half2float(h)) * 2048.0f;   // keep residual normal-range
            lo[p] = __half_as_ushort(__float2half_rn(resid));
        }
    } else if (b < 56) {                   // Wcomb = W4@Wfc ; bcomb = b4@Wfc + bfc
        int id = (b - 48) * 256 + t;       // 2048 threads
        #pragma unroll
        for (int q = 0; q < 4; ++q) {
            int p = id + q * 2048;         // 8192 outputs
            int k = p >> 6, n = p & 63;
            float s = 0.f;
            for (int j = 0; j < D; ++j) s += W4[k * D + j] * Wfc[j * OD + n];
            Wcomb[p] = s;
        }
        if (id < OD) {
            float s = bfc[id];
            for (int j = 0; j < D; ++j) s += b4[j] * Wfc[j * OD + id];
            bcomb[id] = s;
        }
    } else {                               // x -> fp16
        for (int i = (b - 56) * 256 + t; i < NN * D / 4; i += 1600 * 256) {
            float4 v = ((const float4*)x)[i];
            H4 o;
            o.a = __floats2half2_rn(v.x, v.y);
            o.b = __floats2half2_rn(v.z, v.w);
            ((H4*)xh)[i] = o;
        }
    }
}

// ---------------- CSR build ----------------
__global__ void k_count_rank(const int* __restrict__ col,
                             int* __restrict__ counts, int* __restrict__ rank) {
    int e = blockIdx.x * blockDim.x + threadIdx.x;
    if (e < NE) rank[e] = atomicAdd(&counts[col[e]], 1);
}

__global__ __launch_bounds__(256) void k_scan_blk(const int* __restrict__ counts,
                                                  int* __restrict__ offs,
                                                  int* __restrict__ bsum) {
    __shared__ int tmp[256];
    int b = blockIdx.x, t = threadIdx.x;
    int i = b * 256 + t;
    int v = (i < NN) ? counts[i] : 0;
    tmp[t] = v;
    __syncthreads();
    for (int st = 1; st < 256; st <<= 1) {
        int u = (t >= st) ? tmp[t - st] : 0;
        __syncthreads();
        tmp[t] += u;
        __syncthreads();
    }
    if (i < NN) offs[i] = tmp[t] - v;
    if (t == 255) bsum[b] = tmp[255];
}

__global__ __launch_bounds__(256) void k_scan_top(const int* __restrict__ bsum,
                                                  int* __restrict__ bbase, int nb) {
    __shared__ int tmp[256];
    int t = threadIdx.x;
    int v = (t < nb) ? bsum[t] : 0;
    tmp[t] = v;
    __syncthreads();
    for (int st = 1; st < 256; st <<= 1) {
        int u = (t >= st) ? tmp[t - st] : 0;
        __syncthreads();
        tmp[t] += u;
        __syncthreads();
    }
    if (t < nb) bbase[t] = tmp[t] - v;
}

__global__ __launch_bounds__(256) void k_scan_add(int* __restrict__ offs,
                                                  const int* __restrict__ bbase) {
    int b = blockIdx.x, t = threadIdx.x;
    int i = b * 256 + t;
    if (i < NN) offs[i] += bbase[b];
    if (b == 0 && t == 0) offs[NN] = NE;
}

__global__ void k_fill2(const int* __restrict__ row, const int* __restrict__ col,
                        const float* __restrict__ ew, const int* __restrict__ offs,
                        const int* __restrict__ rank, ER* __restrict__ esr) {
    int e = blockIdx.x * blockDim.x + threadIdx.x;
    if (e < NE) {
        ER v;
        v.r = row[e];
        v.w = ew[e];
        esr[offs[col[e]] + rank[e]] = v;
    }
}

__global__ void k_deg_csr(const ER* __restrict__ esr, const int* __restrict__ offs,
                          float* __restrict__ dinv, float* __restrict__ selfc) {
    int i = blockIdx.x * blockDim.x + threadIdx.x;
    if (i < NN) {
        float s = 1.0f;
        int a = offs[i], b = offs[i + 1];
        for (int j = a; j < b; ++j) s += esr[j].w;
        float r = rsqrtf(s);
        dinv[i] = r;
        selfc[i] = r * r;
    }
}

// ---------------- MFMA GEMM: H(fp16) = relu(A @ W + b) (fp16 A direct, 2-term W) ----------------
__global__ __launch_bounds__(512) void k_gemm_mfma(const __half* __restrict__ A,
                                                   const unsigned short* __restrict__ Wl,
                                                   const float* __restrict__ bias,
                                                   __half* __restrict__ H) {
    __shared__ unsigned short Ws[32768];       // hi[16384] | lo[16384] = 64 KB
    int t = threadIdx.x;
    {
        const float4* src = (const float4*)Wl;
        float4* dst = (float4*)Ws;
        #pragma unroll
        for (int i = 0; i < 8; ++i) dst[t + i * 512] = src[t + i * 512];
    }
    __syncthreads();

    int wid = blockIdx.x * 8 + (t >> 6);
    if (wid >= NN / 16) return;                 // 3125 tiles
    int lane = t & 63;
    int r = wid * 16 + (lane & 15);
    int kg = (lane >> 4) << 3;

    f16x8 Af[4];
    const _Float16* ar = (const _Float16*)A + (size_t)r * D + kg;
    #pragma unroll
    for (int s = 0; s < 4; ++s) Af[s] = *(const f16x8*)(ar + s * 32);

    const _Float16* whp = (const _Float16*)Ws;
    const _Float16* wlp = (const _Float16*)(Ws + 16384);
    int cb = lane & 15;
    int rb = wid * 16 + ((lane >> 4) << 2);
    #pragma unroll
    for (int nt = 0; nt < 8; ++nt) {
        f4v acc1 = {0.f, 0.f, 0.f, 0.f};
        f4v acc2 = {0.f, 0.f, 0.f, 0.f};
        #pragma unroll
        for (int s = 0; s < 4; ++s) {
            int off = ((nt * 4 + s) * 64 + lane) * 8;
            f16x8 bh = *(const f16x8*)(whp + off);
            f16x8 bl = *(const f16x8*)(wlp + off);
            acc1 = __builtin_amdgcn_mfma_f32_16x16x32_f16(Af[s], bh, acc1, 0, 0, 0);
            acc2 = __builtin_amdgcn_mfma_f32_16x16x32_f16(Af[s], bl, acc2, 0, 0, 0);
        }
        float bv = bias[nt * 16 + cb];
        __half* hp = H + (size_t)rb * D + nt * 16 + cb;
        #pragma unroll
        for (int q = 0; q < 4; ++q) {
            float v = fmaxf(acc1[q] + acc2[q] * (1.0f / 2048.0f) + bv, 0.f);
            hp[q * D] = __float2half(v);
        }
    }
}

// ---------------- aggregation: out = selfc*H[c] + sum w*H[r] (fp16 in/out, 8-deep ILP) ----------------
// NORM=1 (layer 1): also normalize esr.w in place (w = dinv[c]*ew*dinv[r]); lane 0 writes back.
template <int NORM>
__global__ __launch_bounds__(256) void k_agg(const __half* __restrict__ Hm,
                                             const int* __restrict__ offs,
                                             ER* __restrict__ esr,
                                             const float* __restrict__ dinv,
                                             const float* __restrict__ selfc,
                                             __half* __restrict__ out) {
    int node = blockIdx.x * 8 + (threadIdx.x >> 5);
    if (node >= NN) return;
    int ln = threadIdx.x & 31;
    int l4 = ln * 4;
    H4 sv = *(const H4*)(Hm + (size_t)node * D + l4);
    float2 s0 = __half22float2(sv.a), s1 = __half22float2(sv.b);
    float sc = selfc[node];
    float ax = sc * s0.x, ay = sc * s0.y, az = sc * s1.x, aw = sc * s1.y;
    int s = offs[node], e = offs[node + 1];
    float di = NORM ? dinv[node] : 0.f;
    int j = s;
    for (; j + 8 <= e; j += 8) {
        ER er[8];
        #pragma unroll
        for (int q = 0; q < 8; ++q) er[q] = esr[j + q];
        if (NORM) {
            #pragma unroll
            for (int q = 0; q < 8; ++q) er[q].w = di * er[q].w * dinv[er[q].r];
        }
        H4 v[8];
        #pragma unroll
        for (int q = 0; q < 8; ++q) v[q] = *(const H4*)(Hm + (size_t)er[q].r * D + l4);
        if (NORM && ln == 0) {
            #pragma unroll
            for (int q = 0; q < 8; ++q) esr[j + q].w = er[q].w;
        }
        #pragma unroll
        for (int q = 0; q < 8; ++q) {
            float w = er[q].w;
            float2 p0 = __half22float2(v[q].a), p1 = __half22float2(v[q].b);
            ax += w * p0.x; ay += w * p0.y; az += w * p1.x; aw += w * p1.y;
        }
    }
    for (; j < e; ++j) {
        ER er = esr[j];
        if (NORM) {
            er.w = di * er.w * dinv[er.r];
            if (ln == 0) esr[j].w = er.w;
        }
        H4 v0 = *(const H4*)(Hm + (size_t)er.r * D + l4);
        float2 p0 = __half22float2(v0.a), p1 = __half22float2(v0.b);
        ax += er.w * p0.x; ay += er.w * p0.y; az += er.w * p1.x; aw += er.w * p1.y;
    }
    H4 o;
    o.a = __floats2half2_rn(ax, ay);
    o.b = __floats2half2_rn(az, aw);
    *(H4*)(out + (size_t)node * D + l4) = o;
}

// ---------------- fused mean-pool + output GEMM ----------------
__global__ __launch_bounds__(128) void k_poolout(const __half* __restrict__ Hm,
                                                 const int* __restrict__ batch,
                                                 const float* __restrict__ Wcomb,
                                                 const float* __restrict__ bcomb,
                                                 float* __restrict__ outp) {
    __shared__ float prow[D];
    __shared__ int seb[2];
    int g = blockIdx.x, t = threadIdx.x;
    if (t < 2) {
        int target = g + t;
        int lo = 0, hi = NN;
        while (lo < hi) {
            int mid = (lo + hi) >> 1;
            if (batch[mid] < target) lo = mid + 1; else hi = mid;
        }
        seb[t] = lo;
    }
    __syncthreads();
    int s = seb[0], e = seb[1];
    float a0 = 0.f, a1 = 0.f, a2 = 0.f, a3 = 0.f;
    int n = s;
    for (; n + 4 <= e; n += 4) {
        a0 += __half2float(Hm[(size_t)(n + 0) * D + t]);
        a1 += __half2float(Hm[(size_t)(n + 1) * D + t]);
        a2 += __half2float(Hm[(size_t)(n + 2) * D + t]);
        a3 += __half2float(Hm[(size_t)(n + 3) * D + t]);
    }
    for (; n < e; ++n) a0 += __half2float(Hm[(size_t)n * D + t]);
    float inv = 1.0f / (float)max(e - s, 1);
    prow[t] = (a0 + a1 + a2 + a3) * inv;
    __syncthreads();
    if (t < OD) {
        float acc = bcomb[t];
        #pragma unroll 4
        for (int k = 0; k < D; ++k) acc += prow[k] * Wcomb[k * OD + t];
        outp[g * OD + t] = acc;
    }
}

// ---------------- launch ----------------

extern "C" void kernel_launch(void* const* d_in, const int* in_sizes, int n_in,
                              void* d_out, int out_size, void* d_ws, size_t ws_size,
                              hipStream_t stream) {
    const float* x    = (const float*)d_in[0];
    const int*   ei   = (const int*)d_in[1];
    const int*   row  = ei;
    const int*   col  = ei + NE;
    const float* ew   = (const float*)d_in[2];
    const int*   batch= (const int*)d_in[3];
    const float* W1 = (const float*)d_in[4];  const float* b1 = (const float*)d_in[5];
    const float* W2 = (const float*)d_in[6];  const float* b2 = (const float*)d_in[7];
    const float* W3 = (const float*)d_in[8];  const float* b3 = (const float*)d_in[9];
    const float* W4 = (const float*)d_in[10]; const float* b4 = (const float*)d_in[11];
    const float* Wfc= (const float*)d_in[12]; const float* bfc= (const float*)d_in[13];

    float* ws = (float*)d_ws;
    float* dinv   = ws + 0;                  // 50048
    float* selfc  = ws + 50048;              // 50048
    int*   counts = (int*)(ws + 100096);     // 50176
    int*   offs   = (int*)(ws + 150272);     // 50176
    int*   rank   = (int*)(ws + 200448);     // 500000
    ER*    esr    = (ER*)(ws + 700448);      // 500000 * 8B
    __half* xh    = (__half*)(ws + 1700448); // 6.4M fp16
    __half* bufA  = (__half*)(ws + 4900448); // 6.4M fp16
    __half* bufB  = (__half*)(ws + 8100448); // 6.4M fp16
    unsigned short* wpk = (unsigned short*)(ws + 11300448);  // 3*32768 ushort
    float* wcomb  = ws + 11349600;           // 8192
    float* bcomb  = ws + 11357792;           // 64
    int*   bsum   = (int*)(ws + 11357856);   // 256
    int*   bbase  = (int*)(ws + 11358112);   // 256

    const int TB = 256;
    int nblk = (NN + TB - 1) / TB;   // 196
    int eblk = (NE + TB - 1) / TB;   // 1954

    // fused setup, then CSR build
    k_setup<<<1656, 256, 0, stream>>>(x, W1, W2, W3, W4, Wfc, b4, bfc,
                                      counts, wpk, wcomb, bcomb, xh);
    k_count_rank<<<eblk, TB, 0, stream>>>(col, counts, rank);
    k_scan_blk<<<nblk, 256, 0, stream>>>(counts, offs, bsum);
    k_scan_top<<<1, 256, 0, stream>>>(bsum, bbase, nblk);
    k_scan_add<<<nblk, 256, 0, stream>>>(offs, bbase);
    k_fill2<<<eblk, TB, 0, stream>>>(row, col, ew, offs, rank, esr);
    k_deg_csr<<<nblk, TB, 0, stream>>>(esr, offs, dinv, selfc);

    const int GB = (NN / 16 + 7) / 8;    // 391 gemm blocks (8 waves each)
    const int AB = (NN + 7) / 8;         // 6250 agg blocks

    unsigned short* wp1 = wpk;
    unsigned short* wp2 = wpk + 32768;
    unsigned short* wp3 = wpk + 65536;

    // layers (aggregate-first: h_out = relu((Â h_in) W + b)); layer-1 agg folds edge normalization
    k_agg<1><<<AB, 256, 0, stream>>>(xh,   offs, esr, dinv, selfc, bufA);
    k_gemm_mfma<<<GB, 512, 0, stream>>>(bufA, wp1, b1, bufB);
    k_agg<0><<<AB, 256, 0, stream>>>(bufB, offs, esr, dinv, selfc, bufA);
    k_gemm_mfma<<<GB, 512, 0, stream>>>(bufA, wp2, b2, bufB);
    k_agg<0><<<AB, 256, 0, stream>>>(bufB, offs, esr, dinv, selfc, bufA);
    k_gemm_mfma<<<GB, 512, 0, stream>>>(bufA, wp3, b3, bufB);
    k_agg<0><<<AB, 256, 0, stream>>>(bufB, offs, esr, dinv, selfc, bufA);

    // tail: fused mean-pool + (W4@Wfc) GEMM
    k_poolout<<<NG, 128, 0, stream>>>(bufA, batch, wcomb, bcomb, (float*)d_out);
}